// Round 7
// baseline (644.184 us; speedup 1.0000x reference)
//
#include <hip/hip_runtime.h>
#include <math.h>

typedef float f32x4 __attribute__((ext_vector_type(4)));

// ---------------------------------------------------------------------------
// Kernel 1: sinusoidal embed + Linear/SiLU x2 -> h2 into workspace (4 MB).
// Exact R6 compute pipeline (verified correct); only the tail changed:
// coalesced 1-KB/block write of h2 instead of the 128-KB broadcast.
// 4096 blocks x 256 threads, 2 batches/block.
// ---------------------------------------------------------------------------
__global__ __launch_bounds__(256) void k_mlp(
    const float* __restrict__ t,
    const float* __restrict__ W1, const float* __restrict__ b1,
    const float* __restrict__ W2, const float* __restrict__ b2,
    float* __restrict__ hs)
{
    __shared__ float emb[2][128];
    __shared__ float h1[2][128];
    __shared__ float h2[2][128];

    const int tid  = threadIdx.x;
    const int base = blockIdx.x * 2;

    if (tid < 128) {
        int b = tid >> 6, k = tid & 63;
        double a   = (double)k * (6.907755278982137 / 63.0);
        float freq = (float)exp(a);
        float ang  = 6.2831853071795865f * freq;
        float ph   = t[base + b] * ang;
        float sv, cv;
        sincosf(ph, &sv, &cv);
        emb[b][k]      = sv;
        emb[b][64 + k] = cv;
    }
    __syncthreads();

    const int b  = tid >> 7;     // wave-uniform
    const int jj = tid & 127;

    {
        float acc = b1[jj];
        const float4* e = (const float4*)emb[b];
        const float4* w = (const float4*)(W1 + jj * 128);
        #pragma unroll
        for (int k4 = 0; k4 < 32; ++k4) {
            float4 wv = w[k4], ev = e[k4];
            acc = fmaf(wv.x, ev.x, acc); acc = fmaf(wv.y, ev.y, acc);
            acc = fmaf(wv.z, ev.z, acc); acc = fmaf(wv.w, ev.w, acc);
        }
        acc = acc / (1.0f + expf(-acc));   // SiLU
        h1[b][jj] = acc;
    }
    __syncthreads();

    {
        float acc = b2[jj];
        const float4* e = (const float4*)h1[b];
        const float4* w = (const float4*)(W2 + jj * 128);
        #pragma unroll
        for (int k4 = 0; k4 < 32; ++k4) {
            float4 wv = w[k4], ev = e[k4];
            acc = fmaf(wv.x, ev.x, acc); acc = fmaf(wv.y, ev.y, acc);
            acc = fmaf(wv.z, ev.z, acc); acc = fmaf(wv.w, ev.w, acc);
        }
        acc = acc / (1.0f + expf(-acc));   // SiLU
        h2[b][jj] = acc;
    }
    __syncthreads();

    // coalesced write: h2[2][128] -> hs[base*128 .. base*128+255]
    hs[(size_t)base * 128 + tid] = (&h2[0][0])[tid];
}

// ---------------------------------------------------------------------------
// Kernel 2: pure broadcast store. 1 tile (batch) per block, 8192 blocks.
// Prologue = one 16-B L2-resident load; then 16 loop-invariant float4
// stores per thread (structurally identical to the 6.3 TB/s fill stream).
// out[b,0,i,j] = h2[b,j].
// ---------------------------------------------------------------------------
__global__ __launch_bounds__(256) void k_bcast(
    const float* __restrict__ hs, float* __restrict__ out)
{
    const int tid = threadIdx.x;
    const size_t b = blockIdx.x;
    // chunk g = c*256+tid of 4096 per tile; in-row chunk = g&31 = tid&31
    f32x4 v = ((const f32x4*)(hs + b * 128))[tid & 31];
    f32x4* d = (f32x4*)(out + b * 16384);
    #pragma unroll
    for (int c = 0; c < 16; ++c) {
        d[c * 256 + tid] = v;
    }
}

extern "C" void kernel_launch(void* const* d_in, const int* in_sizes, int n_in,
                              void* d_out, int out_size, void* d_ws, size_t ws_size,
                              hipStream_t stream) {
    const float* t  = (const float*)d_in[0];
    const float* W1 = (const float*)d_in[1];
    const float* b1 = (const float*)d_in[2];
    const float* W2 = (const float*)d_in[3];
    const float* b2 = (const float*)d_in[4];
    float* out = (float*)d_out;
    float* hs  = (float*)d_ws;          // 8192*128 f32 = 4 MB scratch
    const int B = in_sizes[0];          // 8192

    k_mlp  <<<B / 2, 256, 0, stream>>>(t, W1, b1, W2, b2, hs);
    k_bcast<<<B,     256, 0, stream>>>(hs, out);
}

// Round 8
// 549.670 us; speedup vs baseline: 1.1719x; 1.1719x over previous
//
#include <hip/hip_runtime.h>
#include <math.h>

typedef float f32x4 __attribute__((ext_vector_type(4)));

// ---------------------------------------------------------------------------
// Kernel 1: sinusoidal embed + Linear/SiLU x2 -> h2 into workspace (4 MB).
// 512 blocks x 256 threads, 16 batches/block.
// Key change vs R6/R7: the uncoalesced per-neuron weight-row reads (64 L1
// txns per wave-load) are amortized over 16 batches -> 8x less TA pressure
// than R6 (16 blocks/CU -> 2 blocks/CU reading the same 128 KB of weights).
// Each thread keeps 8 batch-accumulators in registers per layer, so each
// weight float4 is loaded once and used 32 times.
// ---------------------------------------------------------------------------
__global__ __launch_bounds__(256) void k_mlp(
    const float* __restrict__ t,
    const float* __restrict__ W1, const float* __restrict__ b1,
    const float* __restrict__ W2, const float* __restrict__ b2,
    float* __restrict__ hs)
{
    __shared__ __attribute__((aligned(16))) float emb[16][128];  // 8 KB
    __shared__ __attribute__((aligned(16))) float h1[16][128];   // 8 KB

    const int tid  = threadIdx.x;
    const int base = blockIdx.x * 16;

    // --- embedding: 16 batches x 64 freqs = 1024 sincos, 4 per thread ---
    #pragma unroll
    for (int i = 0; i < 4; ++i) {
        int idx = i * 256 + tid;          // [0,1024)
        int b   = idx >> 6;               // [0,16)
        int k   = idx & 63;               // [0,64)
        double a   = (double)k * (6.907755278982137 / 63.0);
        float freq = (float)exp(a);
        float ang  = 6.2831853071795865f * freq;
        float ph   = t[base + b] * ang;
        float sv, cv;
        sincosf(ph, &sv, &cv);
        emb[b][k]      = sv;
        emb[b][64 + k] = cv;
    }
    __syncthreads();

    const int jj   = tid & 127;   // neuron
    const int half = tid >> 7;    // wave-uniform: batches half*8 .. half*8+7

    // --- layer 1: h1[b][jj] = silu(b1[jj] + sum_k emb[b][k]*W1[jj,k]) ---
    {
        float acc[8];
        float bv = b1[jj];
        #pragma unroll
        for (int m = 0; m < 8; ++m) acc[m] = bv;
        const float4* w = (const float4*)(W1 + jj * 128);
        #pragma unroll
        for (int k4 = 0; k4 < 32; ++k4) {
            float4 wv = w[k4];
            #pragma unroll
            for (int m = 0; m < 8; ++m) {
                // wave-uniform address -> LDS broadcast (free)
                float4 ev = ((const float4*)emb[half * 8 + m])[k4];
                acc[m] = fmaf(wv.x, ev.x, acc[m]);
                acc[m] = fmaf(wv.y, ev.y, acc[m]);
                acc[m] = fmaf(wv.z, ev.z, acc[m]);
                acc[m] = fmaf(wv.w, ev.w, acc[m]);
            }
        }
        #pragma unroll
        for (int m = 0; m < 8; ++m) {
            float a = acc[m];
            h1[half * 8 + m][jj] = a / (1.0f + expf(-a));   // SiLU
        }
    }
    __syncthreads();

    // --- layer 2: hs[base+b][jj] = silu(b2[jj] + sum_k h1[b][k]*W2[jj,k]) ---
    {
        float acc[8];
        float bv = b2[jj];
        #pragma unroll
        for (int m = 0; m < 8; ++m) acc[m] = bv;
        const float4* w = (const float4*)(W2 + jj * 128);
        #pragma unroll
        for (int k4 = 0; k4 < 32; ++k4) {
            float4 wv = w[k4];
            #pragma unroll
            for (int m = 0; m < 8; ++m) {
                float4 ev = ((const float4*)h1[half * 8 + m])[k4];
                acc[m] = fmaf(wv.x, ev.x, acc[m]);
                acc[m] = fmaf(wv.y, ev.y, acc[m]);
                acc[m] = fmaf(wv.z, ev.z, acc[m]);
                acc[m] = fmaf(wv.w, ev.w, acc[m]);
            }
        }
        #pragma unroll
        for (int m = 0; m < 8; ++m) {
            float a = acc[m];
            // coalesced: lanes jj=0..63 -> consecutive f32
            hs[(size_t)(base + half * 8 + m) * 128 + jj] = a / (1.0f + expf(-a));
        }
    }
}

// ---------------------------------------------------------------------------
// Kernel 2: pure broadcast store. 1 tile (batch) per block, 8192 blocks.
// One 16-B load, then 16 loop-invariant float4 stores per thread
// (structurally the 6.3 TB/s fill stream). out[b,0,i,j] = h2[b,j].
// ---------------------------------------------------------------------------
__global__ __launch_bounds__(256) void k_bcast(
    const float* __restrict__ hs, float* __restrict__ out)
{
    const int tid = threadIdx.x;
    const size_t b = blockIdx.x;
    f32x4 v = ((const f32x4*)(hs + b * 128))[tid & 31];
    f32x4* d = (f32x4*)(out + b * 16384);
    #pragma unroll
    for (int c = 0; c < 16; ++c) {
        d[c * 256 + tid] = v;
    }
}

extern "C" void kernel_launch(void* const* d_in, const int* in_sizes, int n_in,
                              void* d_out, int out_size, void* d_ws, size_t ws_size,
                              hipStream_t stream) {
    const float* t  = (const float*)d_in[0];
    const float* W1 = (const float*)d_in[1];
    const float* b1 = (const float*)d_in[2];
    const float* W2 = (const float*)d_in[3];
    const float* b2 = (const float*)d_in[4];
    float* out = (float*)d_out;
    float* hs  = (float*)d_ws;          // 8192*128 f32 = 4 MB scratch
    const int B = in_sizes[0];          // 8192

    k_mlp  <<<B / 16, 256, 0, stream>>>(t, W1, b1, W2, b2, hs);
    k_bcast<<<B,      256, 0, stream>>>(hs, out);
}

// Round 9
// 543.174 us; speedup vs baseline: 1.1860x; 1.0120x over previous
//
#include <hip/hip_runtime.h>
#include <math.h>

typedef float f32x4 __attribute__((ext_vector_type(4)));

// ---------------------------------------------------------------------------
// Fully fused: sinusoidal embed + Linear/SiLU x2 + broadcast store.
// FP32 in / FP32 out. 1024 blocks x 256 threads, 8 batches/block.
//
// Weights are staged into LDS TRANSPOSED + XOR-SWIZZLED:
//     WL[k*128 + (j ^ (k&31))] = W[j][k]
//  - global reads: coalesced float4 (fixes R6/R8's 64-way txn-split storm)
//  - LDS staging writes: 4-way bank conflict (x1.58, 128 instr -> cheap)
//  - LDS compute reads (lane jj consecutive): 2 lanes/bank -> free
// Each thread keeps 4 batch-accumulators, so one weight read feeds 16 FMAs.
// 76 KB LDS -> 2 blocks/CU; 1024-block grid = 2 cohorts, so cohort-2 compute
// overlaps cohort-1's store stream.
// Store tail identical to R6 (verified): out[b,0,i,j] = h2[b,j].
// ---------------------------------------------------------------------------
__global__ __launch_bounds__(256) void k_fused(
    const float* __restrict__ t,
    const float* __restrict__ W1, const float* __restrict__ b1,
    const float* __restrict__ W2, const float* __restrict__ b2,
    float* __restrict__ out)
{
    __shared__ float WL[128 * 128];                               // 64 KB
    __shared__ __attribute__((aligned(16))) float emb[8][128];    // 4 KB
    __shared__ __attribute__((aligned(16))) float h1[8][128];     // 4 KB
    __shared__ __attribute__((aligned(16))) float h2[8][128];     // 4 KB

    const int tid  = threadIdx.x;
    const int base = blockIdx.x * 8;
    const int jj   = tid & 127;   // neuron
    const int half = tid >> 7;    // wave-uniform: batches half*4 .. half*4+3

    // ---- stage W1 (coalesced read, transposed+swizzled LDS write) ----
    {
        const f32x4* g = (const f32x4*)W1;     // 4096 float4
        #pragma unroll
        for (int it = 0; it < 16; ++it) {
            int idx4 = it * 256 + tid;         // [0,4096)
            f32x4 q = g[idx4];
            int j  = idx4 >> 5;                // row in W
            int k0 = (idx4 & 31) * 4;          // col base
            #pragma unroll
            for (int i = 0; i < 4; ++i) {
                int k = k0 + i;
                WL[k * 128 + (j ^ (k & 31))] = q[i];
            }
        }
    }
    // ---- embedding: 8 batches x 64 freqs = 512 items, 2/thread ----
    #pragma unroll
    for (int i = 0; i < 2; ++i) {
        int idx = i * 256 + tid;               // [0,512)
        int b = idx >> 6, k = idx & 63;
        double a   = (double)k * (6.907755278982137 / 63.0);
        float freq = (float)exp(a);
        float ang  = 6.2831853071795865f * freq;
        float ph   = t[base + b] * ang;
        float sv, cv;
        sincosf(ph, &sv, &cv);
        emb[b][k]      = sv;
        emb[b][64 + k] = cv;
    }
    __syncthreads();

    // ---- layer 1: h1[b][jj] = silu(b1[jj] + sum_k emb[b][k]*W1[jj,k]) ----
    {
        float acc[4];
        float bv = b1[jj];
        #pragma unroll
        for (int m = 0; m < 4; ++m) acc[m] = bv;
        #pragma unroll
        for (int k4 = 0; k4 < 32; ++k4) {
            const int k0 = k4 * 4;
            float w0 = WL[(k0 + 0) * 128 + (jj ^ ((k0 + 0) & 31))];
            float w1 = WL[(k0 + 1) * 128 + (jj ^ ((k0 + 1) & 31))];
            float w2 = WL[(k0 + 2) * 128 + (jj ^ ((k0 + 2) & 31))];
            float w3 = WL[(k0 + 3) * 128 + (jj ^ ((k0 + 3) & 31))];
            #pragma unroll
            for (int m = 0; m < 4; ++m) {
                float4 ev = ((const float4*)emb[half * 4 + m])[k4]; // broadcast
                acc[m] = fmaf(w0, ev.x, acc[m]);
                acc[m] = fmaf(w1, ev.y, acc[m]);
                acc[m] = fmaf(w2, ev.z, acc[m]);
                acc[m] = fmaf(w3, ev.w, acc[m]);
            }
        }
        #pragma unroll
        for (int m = 0; m < 4; ++m) {
            float a = acc[m];
            h1[half * 4 + m][jj] = a / (1.0f + expf(-a));   // SiLU
        }
    }
    __syncthreads();

    // ---- restage W2 over WL ----
    {
        const f32x4* g = (const f32x4*)W2;
        #pragma unroll
        for (int it = 0; it < 16; ++it) {
            int idx4 = it * 256 + tid;
            f32x4 q = g[idx4];
            int j  = idx4 >> 5;
            int k0 = (idx4 & 31) * 4;
            #pragma unroll
            for (int i = 0; i < 4; ++i) {
                int k = k0 + i;
                WL[k * 128 + (j ^ (k & 31))] = q[i];
            }
        }
    }
    __syncthreads();

    // ---- layer 2: h2[b][jj] = silu(b2[jj] + sum_k h1[b][k]*W2[jj,k]) ----
    {
        float acc[4];
        float bv = b2[jj];
        #pragma unroll
        for (int m = 0; m < 4; ++m) acc[m] = bv;
        #pragma unroll
        for (int k4 = 0; k4 < 32; ++k4) {
            const int k0 = k4 * 4;
            float w0 = WL[(k0 + 0) * 128 + (jj ^ ((k0 + 0) & 31))];
            float w1 = WL[(k0 + 1) * 128 + (jj ^ ((k0 + 1) & 31))];
            float w2 = WL[(k0 + 2) * 128 + (jj ^ ((k0 + 2) & 31))];
            float w3 = WL[(k0 + 3) * 128 + (jj ^ ((k0 + 3) & 31))];
            #pragma unroll
            for (int m = 0; m < 4; ++m) {
                float4 ev = ((const float4*)h1[half * 4 + m])[k4];  // broadcast
                acc[m] = fmaf(w0, ev.x, acc[m]);
                acc[m] = fmaf(w1, ev.y, acc[m]);
                acc[m] = fmaf(w2, ev.z, acc[m]);
                acc[m] = fmaf(w3, ev.w, acc[m]);
            }
        }
        #pragma unroll
        for (int m = 0; m < 4; ++m) {
            float a = acc[m];
            h2[half * 4 + m][jj] = a / (1.0f + expf(-a));   // SiLU
        }
    }
    __syncthreads();

    // ---- broadcast store (verified R6 pattern): tile = 4096 float4 chunks;
    // thread writes chunks g = c*256+tid; in-row chunk = g&31 = tid&31.
    #pragma unroll
    for (int m = 0; m < 8; ++m) {
        f32x4 v = *(const f32x4*)&h2[m][(tid & 31) * 4];
        f32x4* d = (f32x4*)(out + (size_t)(base + m) * 16384);
        #pragma unroll
        for (int c = 0; c < 16; ++c) {
            d[c * 256 + tid] = v;
        }
    }
}

extern "C" void kernel_launch(void* const* d_in, const int* in_sizes, int n_in,
                              void* d_out, int out_size, void* d_ws, size_t ws_size,
                              hipStream_t stream) {
    const float* t  = (const float*)d_in[0];
    const float* W1 = (const float*)d_in[1];
    const float* b1 = (const float*)d_in[2];
    const float* W2 = (const float*)d_in[3];
    const float* b2 = (const float*)d_in[4];
    float* out = (float*)d_out;
    const int B = in_sizes[0];   // 8192

    k_fused<<<B / 8, 256, 0, stream>>>(t, W1, b1, W2, b2, out);
}